// Round 13
// baseline (1291.733 us; speedup 1.0000x reference)
//
#include <hip/hip_runtime.h>
#include <hip/hip_bf16.h>

#define B_GRAPHS 64
#define NPER     2048
#define T_NODES  (B_GRAPHS*NPER)
#define D_DIM    256
#define U_DIM    128
#define TU       384   // 3*U
#define XPW      768   // 2*TU (fwd|bwd)

typedef unsigned short ushortT;
typedef unsigned int   uint32;

typedef __attribute__((ext_vector_type(4))) float  f32x4;
typedef __attribute__((ext_vector_type(8))) __bf16 bf16x8;
typedef _Float16 f16;
typedef __attribute__((ext_vector_type(2))) _Float16 f16x2;

#define GAS __attribute__((address_space(1)))
#define LOG2E_F 1.4426950408889634f

static __device__ __forceinline__ ushortT f2bf(float f) {
  union { float f; uint32 u; } a; a.f = f;
  uint32 u = a.u;
  return (ushortT)((u + 0x7fffu + ((u >> 16) & 1u)) >> 16);   // RTNE
}
static __device__ __forceinline__ float bf2f(ushortT h) {
  union { uint32 u; float f; } a; a.u = ((uint32)h) << 16; return a.f;
}
static __device__ __forceinline__ f16x2 u2h(uint32 u) {
  union { uint32 u; f16x2 h; } x; x.u = u; return x.h;
}
static __device__ __forceinline__ float dot2f(f16x2 a, f16x2 b, float c) {
#if __has_builtin(__builtin_amdgcn_fdot2)
  return __builtin_amdgcn_fdot2(a, b, c, false);
#else
  return c + (float)a.x * (float)b.x + (float)a.y * (float)b.y;
#endif
}
static __device__ __forceinline__ float rcpf(float x) {
#if __has_builtin(__builtin_amdgcn_rcpf)
  return __builtin_amdgcn_rcpf(x);
#else
  return 1.0f / x;
#endif
}
static __device__ __forceinline__ float exp2f_hw(float x) {
#if __has_builtin(__builtin_amdgcn_exp2f)
  return __builtin_amdgcn_exp2f(x);
#else
  return __expf(0.69314718055994531f * x);
#endif
}
static __device__ __forceinline__ ushortT gload_u16(const ushortT* p) {
  return *(const GAS ushortT*)p;
}
static __device__ __forceinline__ void gstore_u16(ushortT* p, ushortT v) {
  *(GAS ushortT*)p = v;
}

// ---------------- prep: Wt[2][768][256] bf16 (transposed concat of K_fwd|K_bwd), b0[2][768] f32
// z,r columns prescaled by log2e; h columns by 2*log2e (rec uses exp2 directly).
__global__ __launch_bounds__(256) void prep_kernel(
    const float* __restrict__ Kf, const float* __restrict__ Kb,
    const float* __restrict__ bfw, const float* __restrict__ bbw,
    ushortT* __restrict__ Wt, float* __restrict__ b0)
{
  int idx = blockIdx.x * 256 + threadIdx.x;
  if (idx < 2 * XPW * D_DIM) {
    int l = idx / (XPW * D_DIM);
    int rem = idx % (XPW * D_DIM);
    int c = rem / D_DIM, k = rem % D_DIM;
    float v = (c < TU) ? Kf[(size_t)l * D_DIM * TU + (size_t)k * TU + c]
                       : Kb[(size_t)l * D_DIM * TU + (size_t)k * TU + (c - TU)];
    float sc = ((c % TU) < 256) ? LOG2E_F : 2.0f * LOG2E_F;
    Wt[idx] = f2bf(v * sc);
  } else {
    int i2 = idx - 2 * XPW * D_DIM;
    if (i2 < 2 * XPW) {
      int l = i2 / XPW, c = i2 % XPW;
      float v = (c < TU) ? bfw[l * 2 * TU + c] : bbw[l * 2 * TU + (c - TU)];
      float sc = ((c % TU) < 256) ? LOG2E_F : 2.0f * LOG2E_F;
      b0[i2] = v * sc;
    }
  }
}

// ---------------- nodeof[g][slot] = node index ; L[g] = leaf count (positions are a perm of 1..L)
__global__ __launch_bounds__(256) void nodeofL_kernel(
    const int* __restrict__ pos, int* __restrict__ nodeof, int* __restrict__ L)
{
  int g = blockIdx.x, tid = threadIdx.x;
  __shared__ int red[256];
  int cnt = 0;
  for (int i = 0; i < NPER / 256; ++i) {
    int t = g * NPER + i * 256 + tid;
    int p = pos[t];
    if (p) { nodeof[g * NPER + p - 1] = t; cnt++; }
  }
  red[tid] = cnt; __syncthreads();
  for (int s = 128; s > 0; s >>= 1) {
    if (tid < s) red[tid] += red[tid + s];
    __syncthreads();
  }
  if (tid == 0) L[g] = red[0];
}

#if __has_builtin(__builtin_amdgcn_global_load_lds)
#define GLD_LDS(gsrc, ldst) \
  __builtin_amdgcn_global_load_lds((const GAS void*)(gsrc), \
                                   (__attribute__((address_space(3))) void*)(ldst), 16, 0, 0)
#define HAVE_GLD_LDS 1
#else
#define HAVE_GLD_LDS 0
#endif

// ---------------- xp[row][768] = A[row][0..255] @ Wt^T + b0   (bf16 MFMA, 128x128 tiles, BK=32)
// mode 0: A row r gathered from states (f32 -> bf16) via nodeof ; mode 1: A = dense bf16 (y)
__global__ __launch_bounds__(256) void gemm_kernel(
    const float* __restrict__ statesA, const ushortT* __restrict__ Adense,
    const ushortT* __restrict__ Wt, const float* __restrict__ b0,
    const int* __restrict__ nodeof, const int* __restrict__ L,
    ushortT* __restrict__ xp, int layer, int mode)
{
  int mblk = blockIdx.x, nblk = blockIdx.y;
  int g = mblk >> 4;
  int sBase = (mblk & 15) << 7;
  int Lg = L[g];
  if (sBase >= Lg) return;   // whole row-block is padding

  __shared__ __align__(16) ushortT As[128 * 32];
  __shared__ __align__(16) ushortT Bs[128 * 32];

  int tid = threadIdx.x;
  int lane = tid & 63, wid = tid >> 6;
  int wr = wid >> 1, wc = wid & 1;
  f32x4 acc[4][4];
  for (int i = 0; i < 4; i++) for (int n = 0; n < 4; n++) acc[i][n] = (f32x4){0.f,0.f,0.f,0.f};

  for (int kb = 0; kb < 8; ++kb) {
    __syncthreads();
    // stage B: Wt tile [128 cols][32 k] (Wt is pre-transposed: row=col, 512B row stride)
    for (int c = 0; c < 2; ++c) {
      int flat = c * 4096 + tid * 16;
      int col = flat >> 6;
      size_t srcB = ((size_t)(layer * XPW + nblk * 128 + col)) * 512 + kb * 64 + (flat & 63);
#if HAVE_GLD_LDS
      GLD_LDS((const char*)Wt + srcB, (char*)Bs + c * 4096 + wid * 1024);
#else
      *(uint4*)((char*)Bs + flat) = *(const uint4*)((const char*)Wt + srcB);
#endif
    }
    // stage A
    if (mode) {
      for (int c = 0; c < 2; ++c) {
        int flat = c * 4096 + tid * 16;
        int row = flat >> 6;
        size_t srcA = ((size_t)(mblk * 128 + row)) * 512 + kb * 64 + (flat & 63);
#if HAVE_GLD_LDS
        GLD_LDS((const char*)Adense + srcA, (char*)As + c * 4096 + wid * 1024);
#else
        *(uint4*)((char*)As + flat) = *(const uint4*)((const char*)Adense + srcA);
#endif
      }
    } else {
      for (int c = 0; c < 2; ++c) {
        int flat = c * 4096 + tid * 16;
        int row = flat >> 6;
        int s = sBase + row;
        if (s < Lg) {
          int nt = nodeof[g * NPER + s];
          const float* sp = statesA + (size_t)nt * D_DIM + kb * 32 + ((flat & 63) >> 1);
          float4 u0 = *(const float4*)sp;
          float4 u1 = *(const float4*)(sp + 4);
          union { ushortT us[8]; uint4 v; } pk;
          pk.us[0] = f2bf(u0.x); pk.us[1] = f2bf(u0.y); pk.us[2] = f2bf(u0.z); pk.us[3] = f2bf(u0.w);
          pk.us[4] = f2bf(u1.x); pk.us[5] = f2bf(u1.y); pk.us[6] = f2bf(u1.z); pk.us[7] = f2bf(u1.w);
          *(uint4*)((char*)As + flat) = pk.v;
        }
      }
    }
    __syncthreads();

    bf16x8 af[4], bfr[4];
    for (int i = 0; i < 4; i++) {
      int off = (wr * 64 + i * 16 + (lane & 15)) * 32 + (lane >> 4) * 8;
      af[i] = *(const bf16x8*)&As[off];
    }
    for (int n = 0; n < 4; n++) {
      int off = (wc * 64 + n * 16 + (lane & 15)) * 32 + (lane >> 4) * 8;
      bfr[n] = *(const bf16x8*)&Bs[off];
    }
    for (int i = 0; i < 4; i++)
      for (int n = 0; n < 4; n++)
        acc[i][n] = __builtin_amdgcn_mfma_f32_16x16x32_bf16(af[i], bfr[n], acc[i][n], 0, 0, 0);
  }

  // epilogue: + bias, store bf16.  C/D layout: col = lane&15, row = (lane>>4)*4 + v
  for (int n = 0; n < 4; n++) {
    int gcol = nblk * 128 + wc * 64 + n * 16 + (lane & 15);
    float bb = b0[layer * XPW + gcol];
    for (int i = 0; i < 4; i++) {
      int rowBase = mblk * 128 + wr * 64 + i * 16 + (lane >> 4) * 4;
      for (int v = 0; v < 4; v++)
        xp[(size_t)(rowBase + v) * XPW + gcol] = f2bf(acc[i][n][v] + bb);
    }
  }
}

// ---------------- recurrence: 1 WG (4 waves, 256 thr) per (graph, dir) — r12 skeleton,
// step body re-ordered for latency overlap:
//   (1) 8x ds_read_b128 of h issued FIRST (only dep: barrier)
//   (2) bf2f of current xp regs + next-step prefetch issue fill the read latency
//   (3) z,r dot blocks -> their 2 bpermutes ISSUE -> h dot block runs UNDER their
//       latency -> h bpermute -> one wait window; z/r sigmoids overlap h shuffle.
// K-half combine via __shfl_xor(32) (proven; permlane abandoned after r3/r4/r11).
// ONE raw s_barrier per step, lgkmcnt-only drain (xp/y traffic vmcnt-only, in flight).
__global__ __launch_bounds__(256) void rec_kernel(
    const ushortT* __restrict__ xp,
    const float* __restrict__ Rf, const float* __restrict__ Rb,
    const float* __restrict__ bfw, const float* __restrict__ bbw,
    const int* __restrict__ L, ushortT* __restrict__ y, int layer)
{
  int g = blockIdx.x, dir = blockIdx.y;
  int Lg = L[g];
  if (Lg == 0) return;
  int tid = threadIdx.x;
  int wave = tid >> 6, lane = tid & 63;
  int jl = lane & 31, half = lane >> 5;
  int j = wave * 32 + jl;                 // 0..127

  __shared__ __align__(16) f16 hpk[2][128];

  const float* R  = (dir ? Rb : Rf) + (size_t)layer * U_DIM * TU;
  const float* b1 = (dir ? bbw : bfw) + layer * 2 * TU + TU;

  // recurrent weights into registers (f16x2 over k-pairs, prescaled)
  f16x2 rz[32], rg[32], rh[32];
  #pragma unroll
  for (int m = 0; m < 32; ++m) {
    int k = half * 64 + 2 * m;
    const float* p0 = R + (size_t)k * TU;
    const float* p1 = p0 + TU;
    f16x2 a, b, c;
    a.x = (f16)(p0[j] * LOG2E_F);                a.y = (f16)(p1[j] * LOG2E_F);
    b.x = (f16)(p0[128 + j] * LOG2E_F);          b.y = (f16)(p1[128 + j] * LOG2E_F);
    c.x = (f16)(p0[256 + j] * (2.0f * LOG2E_F)); c.y = (f16)(p1[256 + j] * (2.0f * LOG2E_F));
    rz[m] = a; rg[m] = b; rh[m] = c;
  }
  float bz = half ? 0.0f : b1[j] * LOG2E_F;
  float br = half ? 0.0f : b1[128 + j] * LOG2E_F;
  float bh = half ? 0.0f : b1[256 + j] * (2.0f * LOG2E_F);

  if (tid < 128) hpk[0][tid] = (f16)0.0f;
  float hreg = 0.0f;
  __syncthreads();

  size_t xbase = (size_t)g * NPER * XPW + (size_t)dir * TU;
  int pos0 = dir ? (Lg - 1) : 0;
  const int xstep = dir ? -XPW : XPW;
  const int ystep = dir ? -D_DIM : D_DIM;
  const ushortT* xnext = xp + xbase + (size_t)pos0 * XPW;     // rolling prefetch ptr
  ushortT* ynext = y + ((size_t)(g * NPER + pos0)) * D_DIM + dir * U_DIM + j;

  // depth-4 prologue (pointer advances unconditionally; loads guarded, so no OOB access)
  ushortT xz0=0,xr0=0,xh0=0, xz1=0,xr1=0,xh1=0, xz2=0,xr2=0,xh2=0, xz3=0,xr3=0,xh3=0;
  { xz0 = gload_u16(xnext+j); xr0 = gload_u16(xnext+128+j); xh0 = gload_u16(xnext+256+j); }
  xnext += xstep;
  if (1 < Lg) { xz1 = gload_u16(xnext+j); xr1 = gload_u16(xnext+128+j); xh1 = gload_u16(xnext+256+j); }
  xnext += xstep;
  if (2 < Lg) { xz2 = gload_u16(xnext+j); xr2 = gload_u16(xnext+128+j); xh2 = gload_u16(xnext+256+j); }
  xnext += xstep;
  if (3 < Lg) { xz3 = gload_u16(xnext+j); xr3 = gload_u16(xnext+128+j); xh3 = gload_u16(xnext+256+j); }
  xnext += xstep;

#define GRU_STEP(P, XZ, XR, XH, SS)                                              \
  {                                                                              \
    const int s_ = (SS);                                                         \
    /* (1) h reads first — only dependence is the barrier */                     \
    const uint4* hv = (const uint4*)&hpk[P][half * 64];                          \
    uint4 q0 = hv[0], q1 = hv[1], q2 = hv[2], q3 = hv[3];                        \
    uint4 q4 = hv[4], q5 = hv[5], q6 = hv[6], q7 = hv[7];                        \
    /* (2) consume current xp regs, then issue next prefetch (fills latency) */  \
    float xzf = bf2f(XZ), xrf = bf2f(XR), xhf = bf2f(XH);                        \
    if (s_ + 4 < Lg) {                                                           \
      XZ = gload_u16(xnext + j);                                                 \
      XR = gload_u16(xnext + 128 + j);                                           \
      XH = gload_u16(xnext + 256 + j);                                           \
    }                                                                            \
    xnext += xstep;                                                              \
    uint32 hw[32];                                                               \
    hw[0]=q0.x; hw[1]=q0.y; hw[2]=q0.z; hw[3]=q0.w;                              \
    hw[4]=q1.x; hw[5]=q1.y; hw[6]=q1.z; hw[7]=q1.w;                              \
    hw[8]=q2.x; hw[9]=q2.y; hw[10]=q2.z; hw[11]=q2.w;                            \
    hw[12]=q3.x; hw[13]=q3.y; hw[14]=q3.z; hw[15]=q3.w;                          \
    hw[16]=q4.x; hw[17]=q4.y; hw[18]=q4.z; hw[19]=q4.w;                          \
    hw[20]=q5.x; hw[21]=q5.y; hw[22]=q5.z; hw[23]=q5.w;                          \
    hw[24]=q6.x; hw[25]=q6.y; hw[26]=q6.z; hw[27]=q6.w;                          \
    hw[28]=q7.x; hw[29]=q7.y; hw[30]=q7.z; hw[31]=q7.w;                          \
    /* (3a) z,r dot blocks */                                                    \
    float az0 = bz, ar0 = br, az1 = 0.f, ar1 = 0.f;                              \
    _Pragma("unroll")                                                            \
    for (int m = 0; m < 32; m += 2) {                                            \
      az0 = dot2f(u2h(hw[m]),   rz[m],   az0);                                   \
      ar0 = dot2f(u2h(hw[m]),   rg[m],   ar0);                                   \
      az1 = dot2f(u2h(hw[m+1]), rz[m+1], az1);                                   \
      ar1 = dot2f(u2h(hw[m+1]), rg[m+1], ar1);                                   \
    }                                                                            \
    float pz = az0 + az1, pr = ar0 + ar1;                                        \
    /* (3b) issue z,r bpermutes; h dots run under their latency */               \
    float sz = __shfl_xor(pz, 32);                                               \
    float sr = __shfl_xor(pr, 32);                                               \
    float ah0 = bh, ah1 = 0.f;                                                   \
    _Pragma("unroll")                                                            \
    for (int m = 0; m < 32; m += 2) {                                            \
      ah0 = dot2f(u2h(hw[m]),   rh[m],   ah0);                                   \
      ah1 = dot2f(u2h(hw[m+1]), rh[m+1], ah1);                                   \
    }                                                                            \
    float ph = ah0 + ah1;                                                        \
    float sh = __shfl_xor(ph, 32);                                               \
    /* (4) gates: z,r start as soon as sz,sr land (overlap sh) */                \
    float hz = pz + sz, hr = pr + sr;                                            \
    float z = rcpf(1.0f + exp2f_hw(-(xzf + hz)));                                \
    float r = rcpf(1.0f + exp2f_hw(-(xrf + hr)));                                \
    float hh = ph + sh;                                                          \
    float a = xhf + r * hh;                                                      \
    float e = exp2f_hw(__builtin_fabsf(a));                                      \
    float th = 1.0f - 2.0f * rcpf(e + 1.0f);                                     \
    float cand = __builtin_copysignf(th, a);                                     \
    float hnew = cand + z * (hreg - cand);                                       \
    hreg = hnew;                                                                 \
    if (half) {                                                                  \
      gstore_u16(ynext, f2bf(hnew));                                             \
    } else {                                                                     \
      hpk[(P) ^ 1][j] = (f16)hnew;                                               \
    }                                                                            \
    ynext += ystep;                                                              \
    asm volatile("s_waitcnt lgkmcnt(0)" ::: "memory");                           \
    __builtin_amdgcn_sched_barrier(0);                                           \
    __builtin_amdgcn_s_barrier();                                                \
    __builtin_amdgcn_sched_barrier(0);                                           \
  }

  for (int s = 0; s < Lg; s += 4) {
    GRU_STEP(0, xz0, xr0, xh0, s);
    if (s + 1 < Lg) GRU_STEP(1, xz1, xr1, xh1, s + 1);
    if (s + 2 < Lg) GRU_STEP(0, xz2, xr2, xh2, s + 2);
    if (s + 3 < Lg) GRU_STEP(1, xz3, xr3, xh3, s + 3);
  }
#undef GRU_STEP
}

// ---------------- unpack: leaf -> y (bf16->f32), non-leaf -> states copy
__global__ __launch_bounds__(256) void unpack_kernel(
    const float* __restrict__ states, const int* __restrict__ pos,
    const ushortT* __restrict__ y, float* __restrict__ out)
{
  int node = blockIdx.x * 4 + (threadIdx.x >> 6);
  int lane = threadIdx.x & 63;
  int p = pos[node];
  int g = node >> 11;
  float4 v;
  if (p) {
    const ushortT* yp = y + (size_t)(g * NPER + p - 1) * D_DIM + lane * 4;
    v = make_float4(bf2f(yp[0]), bf2f(yp[1]), bf2f(yp[2]), bf2f(yp[3]));
  } else {
    v = *(const float4*)(states + (size_t)node * D_DIM + lane * 4);
  }
  *(float4*)(out + (size_t)node * D_DIM + lane * 4) = v;
}

extern "C" void kernel_launch(void* const* d_in, const int* in_sizes, int n_in,
                              void* d_out, int out_size, void* d_ws, size_t ws_size,
                              hipStream_t stream) {
  const float* states = (const float*)d_in[0];
  const int*   pos    = (const int*)d_in[1];
  // d_in[2] graph_sizes (uniform 2048), d_in[3] training (0) — unused
  const float* Kf  = (const float*)d_in[4];
  const float* Rf  = (const float*)d_in[5];
  const float* bfw = (const float*)d_in[6];
  const float* Kb  = (const float*)d_in[7];
  const float* Rb  = (const float*)d_in[8];
  const float* bbw = (const float*)d_in[9];

  char* ws = (char*)d_ws;
  // layout: L(256B) | nodeof(512KB) | Wt(768KB) | b0(6KB) | xp(201.3MB) | y(67.1MB)  ~= 270MB
  int*     L      = (int*)(ws + 0);
  int*     nodeof = (int*)(ws + 256);
  ushortT* Wt     = (ushortT*)(ws + 524544);
  float*   b0     = (float*)(ws + 1310976);
  ushortT* xp     = (ushortT*)(ws + 1317120);
  ushortT* y      = (ushortT*)(ws + 202643712);

  prep_kernel<<<1542, 256, 0, stream>>>(Kf, Kb, bfw, bbw, Wt, b0);
  nodeofL_kernel<<<64, 256, 0, stream>>>(pos, nodeof, L);

  dim3 ggrid(1024, 6);
  dim3 rgrid(64, 2);   // 1 chain per WG (minimal step latency is the only lever)

  // layer 0
  gemm_kernel<<<ggrid, 256, 0, stream>>>(states, (const ushortT*)nullptr, Wt, b0, nodeof, L, xp, 0, 0);
  rec_kernel<<<rgrid, 256, 0, stream>>>(xp, Rf, Rb, bfw, bbw, L, y, 0);
  // layer 1
  gemm_kernel<<<ggrid, 256, 0, stream>>>(states, y, Wt, b0, nodeof, L, xp, 1, 1);
  rec_kernel<<<rgrid, 256, 0, stream>>>(xp, Rf, Rb, bfw, bbw, L, y, 1);

  unpack_kernel<<<32768, 256, 0, stream>>>(states, pos, y, (float*)d_out);
}

// Round 14
// 1242.167 us; speedup vs baseline: 1.0399x; 1.0399x over previous
//
#include <hip/hip_runtime.h>
#include <hip/hip_bf16.h>

#define B_GRAPHS 64
#define NPER     2048
#define T_NODES  (B_GRAPHS*NPER)
#define D_DIM    256
#define U_DIM    128
#define TU       384   // 3*U
#define XPW      768   // 2*TU (fwd|bwd)

typedef unsigned short ushortT;
typedef unsigned int   uint32;

typedef __attribute__((ext_vector_type(4))) float  f32x4;
typedef __attribute__((ext_vector_type(8))) __bf16 bf16x8;
typedef _Float16 f16;
typedef __attribute__((ext_vector_type(2))) _Float16 f16x2;

#define GAS __attribute__((address_space(1)))
#define LOG2E_F 1.4426950408889634f

static __device__ __forceinline__ ushortT f2bf(float f) {
  union { float f; uint32 u; } a; a.f = f;
  uint32 u = a.u;
  return (ushortT)((u + 0x7fffu + ((u >> 16) & 1u)) >> 16);   // RTNE
}
static __device__ __forceinline__ float bf2f(ushortT h) {
  union { uint32 u; float f; } a; a.u = ((uint32)h) << 16; return a.f;
}
static __device__ __forceinline__ f16x2 u2h(uint32 u) {
  union { uint32 u; f16x2 h; } x; x.u = u; return x.h;
}
static __device__ __forceinline__ float dot2f(f16x2 a, f16x2 b, float c) {
#if __has_builtin(__builtin_amdgcn_fdot2)
  return __builtin_amdgcn_fdot2(a, b, c, false);
#else
  return c + (float)a.x * (float)b.x + (float)a.y * (float)b.y;
#endif
}
static __device__ __forceinline__ float rcpf(float x) {
#if __has_builtin(__builtin_amdgcn_rcpf)
  return __builtin_amdgcn_rcpf(x);
#else
  return 1.0f / x;
#endif
}
static __device__ __forceinline__ float exp2f_hw(float x) {
#if __has_builtin(__builtin_amdgcn_exp2f)
  return __builtin_amdgcn_exp2f(x);
#else
  return __expf(0.69314718055994531f * x);
#endif
}
static __device__ __forceinline__ ushortT gload_u16(const ushortT* p) {
  return *(const GAS ushortT*)p;
}
static __device__ __forceinline__ void gstore_u16(ushortT* p, ushortT v) {
  *(GAS ushortT*)p = v;
}

// ---------------- prep: Wt[2][768][256] bf16 (transposed concat of K_fwd|K_bwd), b0[2][768] f32
// z,r columns prescaled by log2e; h columns by 2*log2e (rec uses exp2 directly).
__global__ __launch_bounds__(256) void prep_kernel(
    const float* __restrict__ Kf, const float* __restrict__ Kb,
    const float* __restrict__ bfw, const float* __restrict__ bbw,
    ushortT* __restrict__ Wt, float* __restrict__ b0)
{
  int idx = blockIdx.x * 256 + threadIdx.x;
  if (idx < 2 * XPW * D_DIM) {
    int l = idx / (XPW * D_DIM);
    int rem = idx % (XPW * D_DIM);
    int c = rem / D_DIM, k = rem % D_DIM;
    float v = (c < TU) ? Kf[(size_t)l * D_DIM * TU + (size_t)k * TU + c]
                       : Kb[(size_t)l * D_DIM * TU + (size_t)k * TU + (c - TU)];
    float sc = ((c % TU) < 256) ? LOG2E_F : 2.0f * LOG2E_F;
    Wt[idx] = f2bf(v * sc);
  } else {
    int i2 = idx - 2 * XPW * D_DIM;
    if (i2 < 2 * XPW) {
      int l = i2 / XPW, c = i2 % XPW;
      float v = (c < TU) ? bfw[l * 2 * TU + c] : bbw[l * 2 * TU + (c - TU)];
      float sc = ((c % TU) < 256) ? LOG2E_F : 2.0f * LOG2E_F;
      b0[i2] = v * sc;
    }
  }
}

// ---------------- nodeof[g][slot] = node index ; L[g] = leaf count (positions are a perm of 1..L)
__global__ __launch_bounds__(256) void nodeofL_kernel(
    const int* __restrict__ pos, int* __restrict__ nodeof, int* __restrict__ L)
{
  int g = blockIdx.x, tid = threadIdx.x;
  __shared__ int red[256];
  int cnt = 0;
  for (int i = 0; i < NPER / 256; ++i) {
    int t = g * NPER + i * 256 + tid;
    int p = pos[t];
    if (p) { nodeof[g * NPER + p - 1] = t; cnt++; }
  }
  red[tid] = cnt; __syncthreads();
  for (int s = 128; s > 0; s >>= 1) {
    if (tid < s) red[tid] += red[tid + s];
    __syncthreads();
  }
  if (tid == 0) L[g] = red[0];
}

#if __has_builtin(__builtin_amdgcn_global_load_lds)
#define GLD_LDS(gsrc, ldst) \
  __builtin_amdgcn_global_load_lds((const GAS void*)(gsrc), \
                                   (__attribute__((address_space(3))) void*)(ldst), 16, 0, 0)
#define HAVE_GLD_LDS 1
#else
#define HAVE_GLD_LDS 0
#endif

// ---------------- xp[row][768] = A[row][0..255] @ Wt^T + b0   (bf16 MFMA, 128x128 tiles, BK=32)
// mode 0: A row r gathered from states (f32 -> bf16) via nodeof ; mode 1: A = dense bf16 (y)
__global__ __launch_bounds__(256) void gemm_kernel(
    const float* __restrict__ statesA, const ushortT* __restrict__ Adense,
    const ushortT* __restrict__ Wt, const float* __restrict__ b0,
    const int* __restrict__ nodeof, const int* __restrict__ L,
    ushortT* __restrict__ xp, int layer, int mode)
{
  int mblk = blockIdx.x, nblk = blockIdx.y;
  int g = mblk >> 4;
  int sBase = (mblk & 15) << 7;
  int Lg = L[g];
  if (sBase >= Lg) return;   // whole row-block is padding

  __shared__ __align__(16) ushortT As[128 * 32];
  __shared__ __align__(16) ushortT Bs[128 * 32];

  int tid = threadIdx.x;
  int lane = tid & 63, wid = tid >> 6;
  int wr = wid >> 1, wc = wid & 1;
  f32x4 acc[4][4];
  for (int i = 0; i < 4; i++) for (int n = 0; n < 4; n++) acc[i][n] = (f32x4){0.f,0.f,0.f,0.f};

  for (int kb = 0; kb < 8; ++kb) {
    __syncthreads();
    // stage B: Wt tile [128 cols][32 k] (Wt is pre-transposed: row=col, 512B row stride)
    for (int c = 0; c < 2; ++c) {
      int flat = c * 4096 + tid * 16;
      int col = flat >> 6;
      size_t srcB = ((size_t)(layer * XPW + nblk * 128 + col)) * 512 + kb * 64 + (flat & 63);
#if HAVE_GLD_LDS
      GLD_LDS((const char*)Wt + srcB, (char*)Bs + c * 4096 + wid * 1024);
#else
      *(uint4*)((char*)Bs + flat) = *(const uint4*)((const char*)Wt + srcB);
#endif
    }
    // stage A
    if (mode) {
      for (int c = 0; c < 2; ++c) {
        int flat = c * 4096 + tid * 16;
        int row = flat >> 6;
        size_t srcA = ((size_t)(mblk * 128 + row)) * 512 + kb * 64 + (flat & 63);
#if HAVE_GLD_LDS
        GLD_LDS((const char*)Adense + srcA, (char*)As + c * 4096 + wid * 1024);
#else
        *(uint4*)((char*)As + flat) = *(const uint4*)((const char*)Adense + srcA);
#endif
      }
    } else {
      for (int c = 0; c < 2; ++c) {
        int flat = c * 4096 + tid * 16;
        int row = flat >> 6;
        int s = sBase + row;
        if (s < Lg) {
          int nt = nodeof[g * NPER + s];
          const float* sp = statesA + (size_t)nt * D_DIM + kb * 32 + ((flat & 63) >> 1);
          float4 u0 = *(const float4*)sp;
          float4 u1 = *(const float4*)(sp + 4);
          union { ushortT us[8]; uint4 v; } pk;
          pk.us[0] = f2bf(u0.x); pk.us[1] = f2bf(u0.y); pk.us[2] = f2bf(u0.z); pk.us[3] = f2bf(u0.w);
          pk.us[4] = f2bf(u1.x); pk.us[5] = f2bf(u1.y); pk.us[6] = f2bf(u1.z); pk.us[7] = f2bf(u1.w);
          *(uint4*)((char*)As + flat) = pk.v;
        }
      }
    }
    __syncthreads();

    bf16x8 af[4], bfr[4];
    for (int i = 0; i < 4; i++) {
      int off = (wr * 64 + i * 16 + (lane & 15)) * 32 + (lane >> 4) * 8;
      af[i] = *(const bf16x8*)&As[off];
    }
    for (int n = 0; n < 4; n++) {
      int off = (wc * 64 + n * 16 + (lane & 15)) * 32 + (lane >> 4) * 8;
      bfr[n] = *(const bf16x8*)&Bs[off];
    }
    for (int i = 0; i < 4; i++)
      for (int n = 0; n < 4; n++)
        acc[i][n] = __builtin_amdgcn_mfma_f32_16x16x32_bf16(af[i], bfr[n], acc[i][n], 0, 0, 0);
  }

  // epilogue: + bias, store bf16.  C/D layout: col = lane&15, row = (lane>>4)*4 + v
  for (int n = 0; n < 4; n++) {
    int gcol = nblk * 128 + wc * 64 + n * 16 + (lane & 15);
    float bb = b0[layer * XPW + gcol];
    for (int i = 0; i < 4; i++) {
      int rowBase = mblk * 128 + wr * 64 + i * 16 + (lane >> 4) * 4;
      for (int v = 0; v < 4; v++)
        xp[(size_t)(rowBase + v) * XPW + gcol] = f2bf(acc[i][n][v] + bb);
    }
  }
}

// ---------------- recurrence: 1 WG (4 waves, 256 thr) per (graph, dir) — r12 skeleton
// (r13's manual reorder regressed; compiler's schedule of this body is the optimum found).
// lane layout: j = wave*32+(lane&31) (GRU unit), half = lane>>5 (K half).
// Each lane: 3 gate cols {j,128+j,256+j}, 32 f16x2 R regs/gate (prescaled by log2e / 2log2e).
// K-half combine via ds_bpermute with HOISTED loop-invariant address (saves per-step addr
// recompute vs __shfl_xor; same instruction, proven semantics). h via ping-pong LDS, ONE raw
// s_barrier per step with lgkmcnt-only drain (xp loads / y stores vmcnt-only, stay in flight).
// Depth-4 xp prefetch with rolling pointers.
__global__ __launch_bounds__(256) void rec_kernel(
    const ushortT* __restrict__ xp,
    const float* __restrict__ Rf, const float* __restrict__ Rb,
    const float* __restrict__ bfw, const float* __restrict__ bbw,
    const int* __restrict__ L, ushortT* __restrict__ y, int layer)
{
  int g = blockIdx.x, dir = blockIdx.y;
  int Lg = L[g];
  if (Lg == 0) return;
  int tid = threadIdx.x;
  int wave = tid >> 6, lane = tid & 63;
  int jl = lane & 31, half = lane >> 5;
  int j = wave * 32 + jl;                 // 0..127

  __shared__ __align__(16) f16 hpk[2][128];

  const float* R  = (dir ? Rb : Rf) + (size_t)layer * U_DIM * TU;
  const float* b1 = (dir ? bbw : bfw) + layer * 2 * TU + TU;

  // loop-invariant bpermute byte-address for lane^32 exchange
  const int bpaddr = (lane ^ 32) << 2;

  // recurrent weights into registers (f16x2 over k-pairs, prescaled)
  f16x2 rz[32], rg[32], rh[32];
  #pragma unroll
  for (int m = 0; m < 32; ++m) {
    int k = half * 64 + 2 * m;
    const float* p0 = R + (size_t)k * TU;
    const float* p1 = p0 + TU;
    f16x2 a, b, c;
    a.x = (f16)(p0[j] * LOG2E_F);                a.y = (f16)(p1[j] * LOG2E_F);
    b.x = (f16)(p0[128 + j] * LOG2E_F);          b.y = (f16)(p1[128 + j] * LOG2E_F);
    c.x = (f16)(p0[256 + j] * (2.0f * LOG2E_F)); c.y = (f16)(p1[256 + j] * (2.0f * LOG2E_F));
    rz[m] = a; rg[m] = b; rh[m] = c;
  }
  float bz = half ? 0.0f : b1[j] * LOG2E_F;
  float br = half ? 0.0f : b1[128 + j] * LOG2E_F;
  float bh = half ? 0.0f : b1[256 + j] * (2.0f * LOG2E_F);

  if (tid < 128) hpk[0][tid] = (f16)0.0f;
  float hreg = 0.0f;
  __syncthreads();

  size_t xbase = (size_t)g * NPER * XPW + (size_t)dir * TU;
  int pos0 = dir ? (Lg - 1) : 0;
  const int xstep = dir ? -XPW : XPW;
  const int ystep = dir ? -D_DIM : D_DIM;
  const ushortT* xnext = xp + xbase + (size_t)pos0 * XPW;     // rolling prefetch ptr
  ushortT* ynext = y + ((size_t)(g * NPER + pos0)) * D_DIM + dir * U_DIM + j;

  // depth-4 prologue (pointer advances unconditionally; loads guarded, so no OOB access)
  ushortT xz0=0,xr0=0,xh0=0, xz1=0,xr1=0,xh1=0, xz2=0,xr2=0,xh2=0, xz3=0,xr3=0,xh3=0;
  { xz0 = gload_u16(xnext+j); xr0 = gload_u16(xnext+128+j); xh0 = gload_u16(xnext+256+j); }
  xnext += xstep;
  if (1 < Lg) { xz1 = gload_u16(xnext+j); xr1 = gload_u16(xnext+128+j); xh1 = gload_u16(xnext+256+j); }
  xnext += xstep;
  if (2 < Lg) { xz2 = gload_u16(xnext+j); xr2 = gload_u16(xnext+128+j); xh2 = gload_u16(xnext+256+j); }
  xnext += xstep;
  if (3 < Lg) { xz3 = gload_u16(xnext+j); xr3 = gload_u16(xnext+128+j); xh3 = gload_u16(xnext+256+j); }
  xnext += xstep;

// lane^32 pair-sum with hoisted address (ds_bpermute, identical semantics to __shfl_xor(32))
#define XSUM(V) ((V) + __builtin_bit_cast(float,                                  \
    __builtin_amdgcn_ds_bpermute(bpaddr, __builtin_bit_cast(int, (V)))))

#define GRU_STEP(P, XZ, XR, XH, SS)                                              \
  {                                                                              \
    const int s_ = (SS);                                                         \
    float xzf = bf2f(XZ), xrf = bf2f(XR), xhf = bf2f(XH);                        \
    if (s_ + 4 < Lg) {                                                           \
      XZ = gload_u16(xnext + j);                                                 \
      XR = gload_u16(xnext + 128 + j);                                           \
      XH = gload_u16(xnext + 256 + j);                                           \
    }                                                                            \
    xnext += xstep;                                                              \
    const uint4* hv = (const uint4*)&hpk[P][half * 64];                          \
    uint32 hw[32];                                                               \
    _Pragma("unroll")                                                            \
    for (int q8 = 0; q8 < 8; ++q8) {                                             \
      uint4 v_ = hv[q8];                                                         \
      hw[4*q8] = v_.x; hw[4*q8+1] = v_.y; hw[4*q8+2] = v_.z; hw[4*q8+3] = v_.w;  \
    }                                                                            \
    float az0 = bz, ar0 = br, ah0 = bh, az1 = 0.f, ar1 = 0.f, ah1 = 0.f;         \
    _Pragma("unroll")                                                            \
    for (int m = 0; m < 32; m += 2) {                                            \
      az0 = dot2f(u2h(hw[m]),   rz[m],   az0);                                   \
      ar0 = dot2f(u2h(hw[m]),   rg[m],   ar0);                                   \
      ah0 = dot2f(u2h(hw[m]),   rh[m],   ah0);                                   \
      az1 = dot2f(u2h(hw[m+1]), rz[m+1], az1);                                   \
      ar1 = dot2f(u2h(hw[m+1]), rg[m+1], ar1);                                   \
      ah1 = dot2f(u2h(hw[m+1]), rh[m+1], ah1);                                   \
    }                                                                            \
    float hz = XSUM(az0 + az1);                                                  \
    float hr = XSUM(ar0 + ar1);                                                  \
    float hh = XSUM(ah0 + ah1);                                                  \
    float z = rcpf(1.0f + exp2f_hw(-(xzf + hz)));                                \
    float r = rcpf(1.0f + exp2f_hw(-(xrf + hr)));                                \
    float a = xhf + r * hh;                                                      \
    float e = exp2f_hw(__builtin_fabsf(a));                                      \
    float th = 1.0f - 2.0f * rcpf(e + 1.0f);                                     \
    float cand = __builtin_copysignf(th, a);                                     \
    float hnew = cand + z * (hreg - cand);                                       \
    hreg = hnew;                                                                 \
    if (half) {                                                                  \
      gstore_u16(ynext, f2bf(hnew));                                             \
    } else {                                                                     \
      hpk[(P) ^ 1][j] = (f16)hnew;                                               \
    }                                                                            \
    ynext += ystep;                                                              \
    asm volatile("s_waitcnt lgkmcnt(0)" ::: "memory");                           \
    __builtin_amdgcn_sched_barrier(0);                                           \
    __builtin_amdgcn_s_barrier();                                                \
    __builtin_amdgcn_sched_barrier(0);                                           \
  }

  for (int s = 0; s < Lg; s += 4) {
    GRU_STEP(0, xz0, xr0, xh0, s);
    if (s + 1 < Lg) GRU_STEP(1, xz1, xr1, xh1, s + 1);
    if (s + 2 < Lg) GRU_STEP(0, xz2, xr2, xh2, s + 2);
    if (s + 3 < Lg) GRU_STEP(1, xz3, xr3, xh3, s + 3);
  }
#undef GRU_STEP
#undef XSUM
}

// ---------------- unpack: leaf -> y (bf16->f32), non-leaf -> states copy
__global__ __launch_bounds__(256) void unpack_kernel(
    const float* __restrict__ states, const int* __restrict__ pos,
    const ushortT* __restrict__ y, float* __restrict__ out)
{
  int node = blockIdx.x * 4 + (threadIdx.x >> 6);
  int lane = threadIdx.x & 63;
  int p = pos[node];
  int g = node >> 11;
  float4 v;
  if (p) {
    const ushortT* yp = y + (size_t)(g * NPER + p - 1) * D_DIM + lane * 4;
    v = make_float4(bf2f(yp[0]), bf2f(yp[1]), bf2f(yp[2]), bf2f(yp[3]));
  } else {
    v = *(const float4*)(states + (size_t)node * D_DIM + lane * 4);
  }
  *(float4*)(out + (size_t)node * D_DIM + lane * 4) = v;
}

extern "C" void kernel_launch(void* const* d_in, const int* in_sizes, int n_in,
                              void* d_out, int out_size, void* d_ws, size_t ws_size,
                              hipStream_t stream) {
  const float* states = (const float*)d_in[0];
  const int*   pos    = (const int*)d_in[1];
  // d_in[2] graph_sizes (uniform 2048), d_in[3] training (0) — unused
  const float* Kf  = (const float*)d_in[4];
  const float* Rf  = (const float*)d_in[5];
  const float* bfw = (const float*)d_in[6];
  const float* Kb  = (const float*)d_in[7];
  const float* Rb  = (const float*)d_in[8];
  const float* bbw = (const float*)d_in[9];

  char* ws = (char*)d_ws;
  // layout: L(256B) | nodeof(512KB) | Wt(768KB) | b0(6KB) | xp(201.3MB) | y(67.1MB)  ~= 270MB
  int*     L      = (int*)(ws + 0);
  int*     nodeof = (int*)(ws + 256);
  ushortT* Wt     = (ushortT*)(ws + 524544);
  float*   b0     = (float*)(ws + 1310976);
  ushortT* xp     = (ushortT*)(ws + 1317120);
  ushortT* y      = (ushortT*)(ws + 202643712);

  prep_kernel<<<1542, 256, 0, stream>>>(Kf, Kb, bfw, bbw, Wt, b0);
  nodeofL_kernel<<<64, 256, 0, stream>>>(pos, nodeof, L);

  dim3 ggrid(1024, 6);
  dim3 rgrid(64, 2);   // 1 chain per WG (minimal step latency is the only lever)

  // layer 0
  gemm_kernel<<<ggrid, 256, 0, stream>>>(states, (const ushortT*)nullptr, Wt, b0, nodeof, L, xp, 0, 0);
  rec_kernel<<<rgrid, 256, 0, stream>>>(xp, Rf, Rb, bfw, bbw, L, y, 0);
  // layer 1
  gemm_kernel<<<ggrid, 256, 0, stream>>>(states, y, Wt, b0, nodeof, L, xp, 1, 1);
  rec_kernel<<<rgrid, 256, 0, stream>>>(xp, Rf, Rb, bfw, bbw, L, y, 1);

  unpack_kernel<<<32768, 256, 0, stream>>>(states, pos, y, (float*)d_out);
}